// Round 10
// baseline (269.416 us; speedup 1.0000x reference)
//
#include <hip/hip_runtime.h>
#include <hip/hip_bf16.h>
#include <stdint.h>

// ---------------------------------------------------------------------------
// TensorizedGRU: m[b,l] = sum_{j,k} s[b,j] x[b,k] W[l,j,k]  (l in [0,256): W1||W2)
// R10 = R9 structure, MFMA shape 16x16x32 -> 32x32x16 (2495 vs 2176 TF ubench;
// floor 66 -> 55us; half the MFMA instruction count):
//  - wave tile 64m x 64n = 2x2 tiles of 32x32; block 128x128, 4 waves (2x2).
//  - Wt fragments re-cut to (n32 x k16) 1KB units, one coalesced 1KB
//    wave-load each; barrier-free K-loop, depth-1 ping-pong, XCD-pinned
//    split-K (ks = bx&7), regular stores.
//  - s broadcast via row-PERMUTED Sl2 matching 32x32 C-layout
//    row = (reg&3) + 8*(reg>>2) + 4*(lane>>5): lane reads 16 contiguous
//    floats (4x ds_read_b128, broadcast per half-wave).
// ws layout:
//   Wt   bf16 [256][65536]  @ 0          (33,554,432 B)  frag-ordered (n32,k16)
//   x_bf bf16 [4096][256]   @ 32MiB+2MiB ( 2,097,152 B)
//   Mpart f32 [8][4096][256]@ +2MiB      (33,554,432 B)
// ---------------------------------------------------------------------------

typedef short bf8 __attribute__((ext_vector_type(8)));    // 8 bf16 = 4 VGPRs
typedef float f32x4 __attribute__((ext_vector_type(4)));
typedef float f32x16 __attribute__((ext_vector_type(16)));

static constexpr size_t WT_OFF  = 0;
static constexpr size_t XBF_OFF = 33554432 + 2097152;
static constexpr size_t MP_OFF  = XBF_OFF + 2097152;

// round-to-nearest-even f32 -> bf16 (finite inputs only)
__device__ __forceinline__ unsigned f2bf(float f) {
    unsigned u = __builtin_bit_cast(unsigned, f);
    return (u + 0x7fffu + ((u >> 16) & 1u)) >> 16;
}
__device__ __forceinline__ unsigned pack2bf(float a, float b) {
    return f2bf(a) | (f2bf(b) << 16);
}

// ---------------- prep: fragment-ordered Wt (wave-per-frag) + x cast --------
// Fragment f = n5*4096 + kc  (n5 = n>>5, kc = K>>4), f in [0, 32768).
// Lane l supplies B[n = n5*32 + (l&31)][k = kc*16 + (l>>5)*8 .. +8).
__global__ void prep_wx(const float* __restrict__ W1, const float* __restrict__ W2,
                        const float* __restrict__ in0, const float* __restrict__ in1,
                        uint4* __restrict__ Wt, unsigned* __restrict__ x_bf) {
    int bx = blockIdx.x;
    if (bx < 8192) {
        const int tid  = threadIdx.x;
        const int lane = tid & 63, wave = tid >> 6;
        const unsigned f = bx * 4 + wave;
        const unsigned n5 = f >> 12;
        const unsigned kc = f & 4095u;
        const unsigned n = n5 * 32 + (lane & 31);
        const unsigned K = kc * 16 + (lane >> 5) * 8;
        const float* src = (n < 128 ? W1 + ((size_t)n << 16)
                                    : W2 + ((size_t)(n - 128) << 16)) + K;
        float4 a = ((const float4*)src)[0];
        float4 b = ((const float4*)src)[1];
        uint4 o;
        o.x = pack2bf(a.x, a.y); o.y = pack2bf(a.z, a.w);
        o.z = pack2bf(b.x, b.y); o.w = pack2bf(b.z, b.w);
        Wt[(size_t)f * 64 + lane] = o;        // contiguous 1KB per wave
    } else {
        unsigned v = (bx - 8192) * 256 + threadIdx.x; // 262,144 units of 4 elems
        unsigned b = v >> 6;
        unsigned j4 = (v & 63u) * 4u;
        const float* src = (j4 < 128) ? (in0 + (size_t)b * 128 + j4)
                                      : (in1 + (size_t)b * 128 + (j4 - 128));
        float4 a = *(const float4*)src;
        uint2 o;
        o.x = pack2bf(a.x, a.y);
        o.y = pack2bf(a.z, a.w);
        ((uint2*)x_bf)[v] = o;
    }
}

// ---------------- main GEMM: 128x128 tile, split-K=8, barrier-free ----------
// grid 512: ks = bx&7 (XCD-pinned), ntb = (bx>>3)&1, mtb = bx>>4 (0..31).
// block 256 = 4 waves (wm,wn in 2x2); wave tile 64m x 64n = 2x2 MFMA tiles.
__launch_bounds__(256, 2)
__global__ void gemm_p(const unsigned char* __restrict__ Wt,
                       const float* __restrict__ st0, const float* __restrict__ st1,
                       const __hip_bfloat16* __restrict__ x_bf,
                       float* __restrict__ Mpart) {
    const int bx = blockIdx.x;
    const int ks = bx & 7;                  // split-K slice, pinned per XCD
    const int ntb = (bx >> 3) & 1;
    const int mtb = bx >> 4;
    const int b0 = mtb << 7, n0 = ntb << 7;
    const int tid  = threadIdx.x;
    const int lane = tid & 63, wave = tid >> 6;
    const int wm = wave & 1, wn = wave >> 1;
    const int l31 = lane & 31, l5 = lane >> 5;

    // s tile, row-permuted for 32x32 C-layout: Sl2[j][p], p = g*32 + h*16 + r
    // maps to source row g*32 + 4h + (r&3) + 8*(r>>2). Stride 132 (pad).
    __shared__ __align__(16) float Sl2[32 * 132];
    for (int idx = tid; idx < 4096; idx += 256) {
        int j = idx >> 7, p = idx & 127;
        int g = p >> 5, t = p & 31, h = t >> 4, r = t & 15;
        int row = g * 32 + 4 * h + (r & 3) + 8 * (r >> 2);
        int jg = ks * 32 + j;
        float v = (jg < 128) ? st0[(size_t)(b0 + row) * 128 + jg]
                             : st1[(size_t)(b0 + row) * 128 + (jg - 128)];
        Sl2[j * 132 + p] = v;
    }
    __syncthreads();                        // the ONLY barrier

    // B-frag bases: n5(nt) = ntb*4 + wn*2 + nt; frag byte = (n5*4096 + kc)*1024
    const unsigned char* rbn[2];
    #pragma unroll
    for (int nt = 0; nt < 2; ++nt)
        rbn[nt] = Wt + ((size_t)(ntb * 4 + wn * 2 + nt) << 22) + lane * 16;
    // s read base: p = (wm*2+mt)*32 + l5*16  (+ j*132, + i*4)
    const float* sB = Sl2 + wm * 64 + l5 * 16;

    f32x16 racc[2][2];
    #pragma unroll
    for (int mt = 0; mt < 2; ++mt)
        #pragma unroll
        for (int nt = 0; nt < 2; ++nt)
            racc[mt][nt] = (f32x16)(0.f);
    const f32x16 zacc = (f32x16)(0.f);

    // chunk c in [0,128): q = c>>5 (x-quadrant, 64k), j = c&31 (local j)
    // kc(c,kf) = (ks*32 + j)*16 + q*4 + kf; byte = kc*1024
    auto kof = [&](int c) {
        return (size_t)((((ks * 32 + (c & 31)) * 16) + (c >> 5) * 4) * 1024);
    };

    bf8 buf[2][2][4];                       // [ping][nt][kf]
    #pragma unroll
    for (int nt = 0; nt < 2; ++nt)
        #pragma unroll
        for (int kf = 0; kf < 4; ++kf)
            buf[0][nt][kf] = *(const bf8*)(rbn[nt] + kof(0) + kf * 1024);

    bf8 a[2][4];                            // x A-frags, reloaded at q boundary

    #pragma unroll 2
    for (int c = 0; c < 128; ++c) {
        const int pp = c & 1;
        const int q = c >> 5, j = c & 31;
        if (j == 0) {                       // new x-quadrant: reload A-frags
            // A[m = l31][k = kf*16 + l5*8 ..+8) of x rows b0+wm*64+mt*32+l31
            const __hip_bfloat16* xb = x_bf + q * 64 + l5 * 8;
            #pragma unroll
            for (int mt = 0; mt < 2; ++mt)
                #pragma unroll
                for (int kf = 0; kf < 4; ++kf)
                    a[mt][kf] = *(const bf8*)(xb + (size_t)(b0 + wm * 64 + mt * 32 + l31) * 256 + kf * 16);
        }
        // prefetch next chunk's B-frags (wraps to 0 on last iter: harmless)
        {
            const size_t k1 = kof((c + 1) & 127);
            #pragma unroll
            for (int nt = 0; nt < 2; ++nt)
                #pragma unroll
                for (int kf = 0; kf < 4; ++kf)
                    buf[pp ^ 1][nt][kf] = *(const bf8*)(rbn[nt] + k1 + kf * 1024);
        }
        // s values: sv4[mt][i] covers regs r = i*4..i*4+3 (broadcast per half-wave)
        f32x4 sv4[2][4];
        #pragma unroll
        for (int mt = 0; mt < 2; ++mt)
            #pragma unroll
            for (int i = 0; i < 4; ++i)
                sv4[mt][i] = *(const f32x4*)(sB + j * 132 + mt * 32 + i * 4);
        // 16 MFMA (32x32x16, 4-chain over kf) + f32 scale-accumulate
        #pragma unroll
        for (int mt = 0; mt < 2; ++mt)
            #pragma unroll
            for (int nt = 0; nt < 2; ++nt) {
                f32x16 m0 = zacc;
                #pragma unroll
                for (int kf = 0; kf < 4; ++kf)
                    m0 = __builtin_amdgcn_mfma_f32_32x32x16_bf16(
                        a[mt][kf], buf[pp][nt][kf], m0, 0, 0, 0);
                #pragma unroll
                for (int r = 0; r < 16; ++r)
                    racc[mt][nt][r] += sv4[mt][r >> 2][r & 3] * m0[r];
            }
    }

    // split-K partial stores; C/D: col = lane&31, row = (r&3)+8*(r>>2)+4*(lane>>5)
    float* mp = Mpart + ((size_t)ks << 20);
    #pragma unroll
    for (int mt = 0; mt < 2; ++mt)
        #pragma unroll
        for (int nt = 0; nt < 2; ++nt) {
            const int nn = n0 + wn * 64 + nt * 32 + l31;
            #pragma unroll
            for (int r = 0; r < 16; ++r) {
                int b = b0 + wm * 64 + mt * 32 + (r & 3) + 8 * (r >> 2) + 4 * l5;
                mp[(size_t)b * 256 + nn] = racc[mt][nt][r];
            }
        }
}

// ---------------- epilogue: reduce split-K, s@W3, activations, blend --------
__global__ void epilogue(const float* __restrict__ st0, const float* __restrict__ st1,
                         const float* __restrict__ b1, const float* __restrict__ b2,
                         const float* __restrict__ W3, const float* __restrict__ Mpart,
                         float* __restrict__ out) {
    const int tid = threadIdx.x;
    const int h = tid & 127, rg = tid >> 7;          // rg in {0,1}
    const int bbase = blockIdx.x * 8;                // 8 rows per block
    __shared__ float srow[8][256];
    #pragma unroll
    for (int i = 0; i < 8; ++i) {
        int idx = i * 256 + tid;
        int r = idx >> 8, j = idx & 255;
        float v = (j < 128) ? st0[(size_t)(bbase + r) * 128 + j]
                            : st1[(size_t)(bbase + r) * 128 + (j - 128)];
        srow[r][j] = v;
    }
    __syncthreads();
    float acc0 = 0.f, acc1 = 0.f, acc2 = 0.f, acc3 = 0.f;
    for (int j = 0; j < 256; ++j) {
        float w = W3[j * 128 + h];
        acc0 += srow[rg][j] * w;
        acc1 += srow[rg + 2][j] * w;
        acc2 += srow[rg + 4][j] * w;
        acc3 += srow[rg + 6][j] * w;
    }
    float accs[4] = {acc0, acc1, acc2, acc3};
    float bb1 = b1[h], bb2 = b2[h];
    #pragma unroll
    for (int i = 0; i < 4; ++i) {
        int b = bbase + rg + i * 2;
        float m1 = 0.f, m2 = 0.f;
        #pragma unroll
        for (int k = 0; k < 8; ++k) {
            m1 += Mpart[((size_t)k << 20) + (size_t)b * 256 + h];
            m2 += Mpart[((size_t)k << 20) + (size_t)b * 256 + 128 + h];
        }
        float u = 1.0f / (1.0f + expf(-(m2 + bb2)));
        float t = tanhf(m1 + bb1);
        out[(size_t)b * 128 + h] = u * t + (1.0f - u) * accs[i];
    }
}

extern "C" void kernel_launch(void* const* d_in, const int* in_sizes, int n_in,
                              void* d_out, int out_size, void* d_ws, size_t ws_size,
                              hipStream_t stream) {
    const float* in0 = (const float*)d_in[0];
    const float* in1 = (const float*)d_in[1];
    const float* st0 = (const float*)d_in[2];
    const float* st1 = (const float*)d_in[3];
    const float* W1  = (const float*)d_in[4];
    const float* b1  = (const float*)d_in[5];
    const float* W2  = (const float*)d_in[6];
    const float* b2  = (const float*)d_in[7];
    const float* W3  = (const float*)d_in[8];
    float* out = (float*)d_out;
    char* ws = (char*)d_ws;

    unsigned char* Wt   = (unsigned char*)(ws + WT_OFF);
    unsigned*      x_bf = (unsigned*)(ws + XBF_OFF);
    float*         Mp   = (float*)(ws + MP_OFF);

    prep_wx<<<9216, 256, 0, stream>>>(W1, W2, in0, in1, (uint4*)Wt, x_bf);
    gemm_p<<<512, 256, 0, stream>>>(Wt, st0, st1, (const __hip_bfloat16*)x_bf, Mp);
    epilogue<<<512, 256, 0, stream>>>(st0, st1, b1, b2, W3, Mp, out);
}